// Round 6
// baseline (786.370 us; speedup 1.0000x reference)
//
#include <hip/hip_runtime.h>

// Problem constants (fixed by the reference)
#define NN   50000
#define EE   800000
#define DD   64
#define HH   128
#define KIN  320          // 5 * 64
#define TILE_E 128        // 128 edges/block, 512 threads, LDS 81920 B -> 2 blocks/CU

typedef __bf16 bf16x8 __attribute__((ext_vector_type(8)));
typedef float  f32x4  __attribute__((ext_vector_type(4)));
typedef float  f32x16 __attribute__((ext_vector_type(16)));

#if __has_builtin(__builtin_amdgcn_cvt_pk_bf16_f32)
typedef __bf16 bf16x2_t __attribute__((ext_vector_type(2)));
__device__ __forceinline__ unsigned int pk2(float a, float b) {
  union { bf16x2_t v; unsigned int u; } cv;
  cv.v = __builtin_amdgcn_cvt_pk_bf16_f32(a, b);
  return cv.u;
}
__device__ __forceinline__ unsigned short f2bf(float a) {
  return (unsigned short)(pk2(a, a) & 0xFFFFu);
}
#else
__device__ __forceinline__ unsigned short f2bf(float f) {
  union { float f; unsigned int u; } v; v.f = f;
  unsigned int u = v.u + 0x7FFFu + ((v.u >> 16) & 1u);   // RTNE
  return (unsigned short)(u >> 16);
}
__device__ __forceinline__ unsigned int pk2(float a, float b) {
  return (unsigned int)f2bf(a) | ((unsigned int)f2bf(b) << 16);
}
#endif

__device__ __forceinline__ float bf2f(unsigned short b) {
  union { unsigned int u; float f; } v; v.u = ((unsigned int)b) << 16; return v.f;
}

// ---------------------------------------------------------------------------
// Packed psi layout in 16B units with a bank-spreading XOR swizzle:
//   raw unit = ((row>>4)*10 + (kk>>5))*64 + (row&15)*4 + ((kk>>3)&3)
//   swizzle:   unit ^= (row>>1)&3        (bijective within each row's 4-unit
//                                          k-quad granule)
// Rationale: A-fragment b128 reads walk rows at 64B stride -> only bank
// groups {0,4} (8-way conflict, the 3.9e7 counter). XOR-ing (row>>1)&3 into
// the k-quad bits makes bank-group = ((row&1)<<2) ^ ((row>>1)&3), distinct
// across 8 consecutive rows -> ~2-way (free). Applied identically at
// gather-write, MFMA reads, h1/h2 writebacks, and epilogue reads.
// ---------------------------------------------------------------------------
__device__ __forceinline__ int psiIdx(int row, int kk) {
  int u = (((row >> 4) * 10 + (kk >> 5)) << 6) + ((row & 15) << 2) + ((kk >> 3) & 3);
  u ^= (row >> 1) & 3;
  return (u << 3) + (kk & 7);
}

// ---------------------------------------------------------------------------
// Fused prep: node tables fp32->bf16, weight transpose fp32->bf16 ([n][k] so
// MFMA B-fragments are 16B runs), agg zeroing. Grid 3381 x 256.
// ---------------------------------------------------------------------------
__global__ __launch_bounds__(256) void prep_all(
    const float* __restrict__ hd, const float* __restrict__ hs,
    const float* __restrict__ W0, const float* __restrict__ W1,
    const float* __restrict__ W2,
    unsigned short* __restrict__ hdb, unsigned short* __restrict__ hsb,
    unsigned short* __restrict__ WT0, unsigned short* __restrict__ WT1,
    unsigned short* __restrict__ WT2, float* __restrict__ agg) {
  int b = blockIdx.x;
  int t = b * 256 + threadIdx.x;
  if (b < 3125) {                          // t in [0, 800000)
    *(float4*)(agg + (size_t)t * 4) = (float4){0.f, 0.f, 0.f, 0.f};  // zero agg
    const int n = NN * DD / 8;             // 400000
    const float* src; unsigned short* dst; int i;
    if (t < n) { src = hd; dst = hdb; i = t; }
    else       { src = hs; dst = hsb; i = t - n; }
    float4 a = *(const float4*)(src + (size_t)i * 8);
    float4 c = *(const float4*)(src + (size_t)i * 8 + 4);
    uint4 w;
    w.x = pk2(a.x, a.y); w.y = pk2(a.z, a.w);
    w.z = pk2(c.x, c.y); w.w = pk2(c.z, c.w);
    *(uint4*)(dst + (size_t)i * 8) = w;
  } else {                                 // weights: u in [0, 65536)
    int u = t - 3125 * 256;
    if (u < KIN * HH) {
      int k = u / HH, n2 = u % HH;
      WT0[n2 * KIN + k] = f2bf(W0[u]);
    } else if (u < KIN * HH + HH * HH) {
      int v = u - KIN * HH; int k = v / HH, n2 = v % HH;
      WT1[n2 * HH + k] = f2bf(W1[v]);
    } else {
      int v = u - KIN * HH - HH * HH; int k = v / DD, n2 = v % DD;
      WT2[n2 * HH + k] = f2bf(W2[v]);
    }
  }
}

// ---------------------------------------------------------------------------
// Fused edge kernel, 32x32x16 MFMA edition. 512 threads (8 waves), 128 edges
// per block, LDS 81920 B -> 2 blocks/CU. Wave tiling: L0/L1 wave (et, hp)
// computes edge-rows [et*32, et*32+32) x cols [hp*32, hp*32+64) -> one A-frag
// feeds 2 MFMAs; psi A-reads drop 1024 -> 288 b128/block vs the 16x16 form.
// W streamed from L2 as B-fragments (col = l&31). Swizzled psi (see psiIdx).
// ---------------------------------------------------------------------------
__global__ __launch_bounds__(512, 4) void edge_mlp(
    const unsigned short* __restrict__ hdb,  // h_d_prev [N][64] bf16
    const unsigned short* __restrict__ hsb,  // h_s      [N][64] bf16
    const float* __restrict__ ef,            // edge_feat[E][64] fp32
    const int* __restrict__ snd,
    const int* __restrict__ rcv,
    const unsigned short* __restrict__ WT0,  // [128][320] bf16
    const float* __restrict__ b0,            // [128]
    const unsigned short* __restrict__ WT1,  // [128][128] bf16
    const float* __restrict__ b1,            // [128]
    const unsigned short* __restrict__ WT2,  // [64][128] bf16
    const float* __restrict__ b2,            // [64]
    float* __restrict__ agg)                 // [N][64] fp32
{
  __shared__ __align__(16) unsigned short psi[TILE_E * KIN];  // 81920 B exactly

  const int tid  = threadIdx.x;
  const int e0   = blockIdx.x * TILE_E;
  const int wv   = tid >> 6;        // 0..7
  const int lane = tid & 63;
  const int l31  = lane & 31;
  const int g2   = lane >> 5;       // 0..1

  const int et = wv & 3;            // edge-row tile (32 rows)
  const int hp = (wv >> 2) << 1;    // L0/L1 col-tile pair base: 0 or 2
  const int nt = wv >> 2;           // L2 col tile: 0..1

  // Receiver rows for the epilogue (32-lane broadcast loads; hidden by gather).
  int rv[16];
  #pragma unroll
  for (int reg = 0; reg < 16; ++reg) {
    int row = et * 32 + (reg & 3) + ((reg >> 2) << 3) + (g2 << 2);
    rv[reg] = rcv[e0 + row];
  }

  // Gather: 10 jobs/thread (5 segs x 2 edge-halves), loads batched into
  // registers, then written to swizzled LDS units.
  {
    const int eA = tid >> 3;          // [0,64)
    const int eB = eA + 64;           // [64,128)
    const int c  = tid & 7;           // 16B chunk of the 320-elem row
    const int sw = (eA >> 1) & 3;     // swizzle (same for eB: +64 keeps bits)
    const int siA = snd[e0 + eA], siB = snd[e0 + eB];
    const int riA = rcv[e0 + eA], riB = rcv[e0 + eB];
    uint4 w[10];
    #pragma unroll
    for (int i = 0; i < 10; ++i) {
      const int seg = i >> 1;                    // compile-time 0..4
      if (seg < 4) {
        const unsigned short* tb = (seg & 2) ? hdb : hsb;   // 0,1=h_s  2,3=h_d
        int ix = (seg & 1) ? ((i & 1) ? riB : riA)
                           : ((i & 1) ? siB : siA);
        w[i] = *(const uint4*)(tb + (size_t)ix * DD + c * 8);
      } else {
        const int e = (i & 1) ? eB : eA;
        const float* src = ef + (size_t)(e0 + e) * DD + c * 8;
        float4 v0 = *(const float4*)(src);
        float4 v1 = *(const float4*)(src + 4);
        w[i].x = pk2(v0.x, v0.y); w[i].y = pk2(v0.z, v0.w);
        w[i].z = pk2(v1.x, v1.y); w[i].w = pk2(v1.z, v1.w);
      }
    }
    #pragma unroll
    for (int i = 0; i < 10; ++i) {
      const int seg = i >> 1;
      const int e   = (i & 1) ? eB : eA;
      int unit = (((e >> 4) * 10 + seg * 2 + (c >> 2)) << 6) + ((e & 15) << 2) + (c & 3);
      unit ^= sw;
      *(uint4*)(&psi[unit * 8]) = w[i];
    }
  }

  const int arow = et * 32 + l31;   // this lane's A-fragment edge-row

  // Preload first L0 B-fragments so the L2 hop overlaps the barrier wait.
  const unsigned short* wb0 = WT0 + (hp * 32 + l31) * KIN + g2 * 8;
  const unsigned short* wb1 = wb0 + 32 * KIN;
  bf16x8 p0[2], p1[2];
  #pragma unroll
  for (int k0 = 0; k0 < 2; ++k0) {
    p0[k0] = *(const bf16x8*)(wb0 + k0 * 16);
    p1[k0] = *(const bf16x8*)(wb1 + k0 * 16);
  }
  __syncthreads();

  f32x16 acc0 = {0,0,0,0,0,0,0,0,0,0,0,0,0,0,0,0};
  f32x16 acc1 = {0,0,0,0,0,0,0,0,0,0,0,0,0,0,0,0};

  // ------------------ Layer 0: [128,320] @ [320,128] -----------------------
  #pragma unroll
  for (int k0 = 0; k0 < 20; ++k0) {
    bf16x8 a   = *(const bf16x8*)(&psi[psiIdx(arow, k0 * 16 + g2 * 8)]);
    bf16x8 bf0 = (k0 < 2) ? p0[k0] : *(const bf16x8*)(wb0 + k0 * 16);
    bf16x8 bf1 = (k0 < 2) ? p1[k0] : *(const bf16x8*)(wb1 + k0 * 16);
    acc0 = __builtin_amdgcn_mfma_f32_32x32x16_bf16(a, bf0, acc0, 0, 0, 0);
    acc1 = __builtin_amdgcn_mfma_f32_32x32x16_bf16(a, bf1, acc1, 0, 0, 0);
  }
  __syncthreads();          // psi input reads done -> safe to overwrite kk[0,128)

  // h1 -> kk [0,128)
  {
    const int col0 = hp * 32 + l31, col1 = col0 + 32;
    float bv0 = b0[col0], bv1 = b0[col1];
    #pragma unroll
    for (int reg = 0; reg < 16; ++reg) {
      int row = et * 32 + (reg & 3) + ((reg >> 2) << 3) + (g2 << 2);
      float v0 = acc0[reg] + bv0; v0 = v0 > 0.f ? v0 : 0.f;
      float v1 = acc1[reg] + bv1; v1 = v1 > 0.f ? v1 : 0.f;
      psi[psiIdx(row, col0)] = f2bf(v0);
      psi[psiIdx(row, col1)] = f2bf(v1);
    }
  }
  __syncthreads();

  // ------------------ Layer 1: [128,128] @ [128,128] -----------------------
  acc0 = (f32x16){0,0,0,0,0,0,0,0,0,0,0,0,0,0,0,0};
  acc1 = (f32x16){0,0,0,0,0,0,0,0,0,0,0,0,0,0,0,0};
  {
    const unsigned short* wc0 = WT1 + (hp * 32 + l31) * HH + g2 * 8;
    const unsigned short* wc1 = wc0 + 32 * HH;
    #pragma unroll
    for (int k0 = 0; k0 < 8; ++k0) {
      bf16x8 a   = *(const bf16x8*)(&psi[psiIdx(arow, k0 * 16 + g2 * 8)]);
      bf16x8 bf0 = *(const bf16x8*)(wc0 + k0 * 16);
      bf16x8 bf1 = *(const bf16x8*)(wc1 + k0 * 16);
      acc0 = __builtin_amdgcn_mfma_f32_32x32x16_bf16(a, bf0, acc0, 0, 0, 0);
      acc1 = __builtin_amdgcn_mfma_f32_32x32x16_bf16(a, bf1, acc1, 0, 0, 0);
    }
  }
  __syncthreads();          // h1 reads done -> overwrite with h2

  {
    const int col0 = hp * 32 + l31, col1 = col0 + 32;
    float bv0 = b1[col0], bv1 = b1[col1];
    #pragma unroll
    for (int reg = 0; reg < 16; ++reg) {
      int row = et * 32 + (reg & 3) + ((reg >> 2) << 3) + (g2 << 2);
      float v0 = acc0[reg] + bv0; v0 = v0 > 0.f ? v0 : 0.f;
      float v1 = acc1[reg] + bv1; v1 = v1 > 0.f ? v1 : 0.f;
      psi[psiIdx(row, col0)] = f2bf(v0);
      psi[psiIdx(row, col1)] = f2bf(v1);
    }
  }
  __syncthreads();

  // ---------- Layer 2: [128,128] @ [128,64] + s_ij + atomic scatter --------
  {
    f32x16 acc2 = {0,0,0,0,0,0,0,0,0,0,0,0,0,0,0,0};
    const unsigned short* wd = WT2 + (nt * 32 + l31) * HH + g2 * 8;
    #pragma unroll
    for (int k0 = 0; k0 < 8; ++k0) {
      bf16x8 a  = *(const bf16x8*)(&psi[psiIdx(arow, k0 * 16 + g2 * 8)]);
      bf16x8 bf = *(const bf16x8*)(wd + k0 * 16);
      acc2 = __builtin_amdgcn_mfma_f32_32x32x16_bf16(a, bf, acc2, 0, 0, 0);
    }
    int   n2 = nt * 32 + l31;
    float bv = b2[n2];
    #pragma unroll
    for (int reg = 0; reg < 16; ++reg) {
      int row = et * 32 + (reg & 3) + ((reg >> 2) << 3) + (g2 << 2);
      float p  = acc2[reg] + bv; p = p > 0.f ? p : 0.f;
      float di = bf2f(psi[psiIdx(row, 128 + n2)]);   // h_d[sender]
      float dj = bf2f(psi[psiIdx(row, 192 + n2)]);   // h_d[receiver]
      float s  = p * (dj - di);
      atomicAdd(&agg[(size_t)rv[reg] * DD + n2], s);
    }
  }
}

// ---------------------------------------------------------------------------
// out = h_d_prev + agg @ Wm  (fp32). 16 rows/block, LDS-staged agg (stride 72
// swizzle: conflict-free broadcast) + float4 Wm reads. Grid 3125.
// ---------------------------------------------------------------------------
__global__ __launch_bounds__(256) void final_out(
    const float* __restrict__ hd,
    const float* __restrict__ agg,
    const float* __restrict__ Wm,   // [64][64] fp32
    float* __restrict__ out)
{
  __shared__ float wmf[DD * DD];    // 16 KB
  __shared__ float arow[16 * 72];   // 4.5 KB, stride-72 swizzle
  int tid = threadIdx.x;
  const float4* wm4 = (const float4*)Wm;
  float4* wf4 = (float4*)wmf;
  #pragma unroll
  for (int i = tid; i < DD * DD / 4; i += 256) wf4[i] = wm4[i];

  int r0 = blockIdx.x * 16;
  {
    float4 av = *(const float4*)(agg + (size_t)r0 * DD + tid * 4);
    int rr = tid >> 4, cc = (tid & 15) * 4;       // tid*4 == rr*64 + cc
    *(float4*)&arow[rr * 72 + cc] = av;
  }
  __syncthreads();

  int row = tid >> 4;
  int cq  = (tid & 15) * 4;
  f32x4 acc = (f32x4){0, 0, 0, 0};
  #pragma unroll
  for (int k = 0; k < DD; ++k) {
    float a = arow[row * 72 + k];
    f32x4 w = *(const f32x4*)&wmf[k * DD + cq];
    acc += a * w;
  }
  size_t o = ((size_t)(r0 + row)) * DD + cq;
  f32x4 h = *(const f32x4*)(hd + o);
  *(f32x4*)(out + o) = h + acc;
}

// ---------------------------------------------------------------------------
extern "C" void kernel_launch(void* const* d_in, const int* in_sizes, int n_in,
                              void* d_out, int out_size, void* d_ws, size_t ws_size,
                              hipStream_t stream) {
  const float* hd = (const float*)d_in[0];
  const float* hs = (const float*)d_in[1];
  const float* ef = (const float*)d_in[2];
  const int* snd  = (const int*)d_in[3];
  const int* rcv  = (const int*)d_in[4];
  const float* W0 = (const float*)d_in[5];
  const float* b0 = (const float*)d_in[6];
  const float* W1 = (const float*)d_in[7];
  const float* b1 = (const float*)d_in[8];
  const float* W2 = (const float*)d_in[9];
  const float* b2 = (const float*)d_in[10];
  const float* Wm = (const float*)d_in[11];
  float* out      = (float*)d_out;

  char* ws = (char*)d_ws;
  float* agg = (float*)ws;                                   // 12,800,000 B
  unsigned short* WT0 = (unsigned short*)(ws + 12800000);    //     81,920 B
  unsigned short* WT1 = WT0 + KIN * HH;                      //     32,768 B
  unsigned short* WT2 = WT1 + HH * HH;                       //     16,384 B
  unsigned short* hdb = WT2 + HH * DD;                       //  6,400,000 B
  unsigned short* hsb = hdb + (size_t)NN * DD;               //  6,400,000 B
                                                             // total ~25.8 MB
  prep_all<<<3381, 256, 0, stream>>>(hd, hs, W0, W1, W2,
                                     hdb, hsb, WT0, WT1, WT2, agg);
  edge_mlp<<<EE / TILE_E, 512, 0, stream>>>(hdb, hsb, ef, snd, rcv,
                                            WT0, b0, WT1, b1, WT2, b2, agg);
  final_out<<<NN / 16, 256, 0, stream>>>(hd, agg, Wm, out);
}